// Round 3
// baseline (998.533 us; speedup 1.0000x reference)
//
#include <hip/hip_runtime.h>
#include <hip/hip_bf16.h>
#include <math.h>

#define NTOK   1024
#define DMODEL 1024
#define NHEADS 16
#define DHEAD  64

// ---------------------------------------------------------------------------
// Kernel 1: geometric bias MLP.  bias[b,h,i,j] = W2^T relu(W1^T (xyz_i-xyz_j) + b1) + b2
// Written into the attn region of d_out (later overwritten by softmax result).
// ---------------------------------------------------------------------------
__global__ __launch_bounds__(256) void bias_kernel(
    const float* __restrict__ xyz,
    const float* __restrict__ W1, const float* __restrict__ b1,
    const float* __restrict__ W2, const float* __restrict__ b2,
    float* __restrict__ attnO)
{
    __shared__ float wbuf[656];
    int tid = threadIdx.x;
    for (int i = tid; i < 656; i += 256) {
        float v;
        if (i < 96)       v = W1[i];
        else if (i < 128) v = b1[i - 96];
        else if (i < 640) v = W2[i - 128];
        else              v = b2[i - 640];
        wbuf[i] = v;
    }
    __syncthreads();
    const float* w1s = wbuf;         // [3][32]
    const float* b1s = wbuf + 96;    // [32]
    const float* w2s = wbuf + 128;   // [32][16]
    const float* b2s = wbuf + 640;   // [16]

    int j = blockIdx.x * 256 + tid;
    int i = blockIdx.y;
    int b = blockIdx.z;

    float xi0 = xyz[((size_t)b * NTOK + i) * 3 + 0];
    float xi1 = xyz[((size_t)b * NTOK + i) * 3 + 1];
    float xi2 = xyz[((size_t)b * NTOK + i) * 3 + 2];
    float d0 = xi0 - xyz[((size_t)b * NTOK + j) * 3 + 0];
    float d1 = xi1 - xyz[((size_t)b * NTOK + j) * 3 + 1];
    float d2 = xi2 - xyz[((size_t)b * NTOK + j) * 3 + 2];

    float h[32];
#pragma unroll
    for (int hh = 0; hh < 32; ++hh) {
        float v = b1s[hh] + d0 * w1s[hh] + d1 * w1s[32 + hh] + d2 * w1s[64 + hh];
        h[hh] = fmaxf(v, 0.f);
    }
    size_t base = (size_t)b * NHEADS * 1048576 + (size_t)i * 1024 + j;
#pragma unroll
    for (int hd = 0; hd < NHEADS; ++hd) {
        float acc = b2s[hd];
#pragma unroll
        for (int hh = 0; hh < 32; ++hh) acc += h[hh] * w2s[hh * 16 + hd];
        attnO[base + (size_t)hd * 1048576] = acc;
    }
}

// ---------------------------------------------------------------------------
// Kernel 2/4: fp32 GEMM  C[2048 x 1024] = A[2048 x 1024] @ W[1024 x 1024] + bias
// BM=128, BN=64, BK=16, 256 threads, 8x4 micro-tile.
// qkv==1: write in [B,H,N,DH] layout; qkv==0: flat [M][1024].
// grid.z selects (W,bias,O) among the three pointer triples.
// ---------------------------------------------------------------------------
__global__ __launch_bounds__(256, 4) void gemm_kernel(
    const float* __restrict__ A,
    const float* __restrict__ Wa, const float* __restrict__ Ba,
    const float* __restrict__ Wb, const float* __restrict__ Bb,
    const float* __restrict__ Wc, const float* __restrict__ Bc,
    float* __restrict__ Oa, float* __restrict__ Ob, float* __restrict__ Oc,
    int qkv)
{
    int z = blockIdx.z;
    const float* W    = (z == 0) ? Wa : (z == 1) ? Wb : Wc;
    const float* bias = (z == 0) ? Ba : (z == 1) ? Bb : Bc;
    float*       O    = (z == 0) ? Oa : (z == 1) ? Ob : Oc;

    __shared__ float As[16][128];
    __shared__ float Bs[16][64];

    int tid = threadIdx.x;
    int tx = tid & 15, ty = tid >> 4;
    int row0 = blockIdx.y * 128;
    int col0 = blockIdx.x * 64;

    float acc[8][4];
#pragma unroll
    for (int i = 0; i < 8; ++i)
#pragma unroll
        for (int j = 0; j < 4; ++j) acc[i][j] = 0.f;

    for (int kt = 0; kt < 64; ++kt) {
        // stage A tile (128x16) transposed -> As[16][128]
#pragma unroll
        for (int i = 0; i < 2; ++i) {
            int id = tid + i * 256;          // 0..511
            int r  = id >> 2;                // 0..127
            int c4 = id & 3;                 // 0..3
            float4 a = *(const float4*)&A[(size_t)(row0 + r) * 1024 + kt * 16 + c4 * 4];
            As[c4 * 4 + 0][r] = a.x;
            As[c4 * 4 + 1][r] = a.y;
            As[c4 * 4 + 2][r] = a.z;
            As[c4 * 4 + 3][r] = a.w;
        }
        // stage B tile (16x64)
        {
            float4 bv = *(const float4*)&W[(size_t)(kt * 16 + ty) * 1024 + col0 + tx * 4];
            *(float4*)&Bs[ty][tx * 4] = bv;
        }
        __syncthreads();
#pragma unroll
        for (int k = 0; k < 16; ++k) {
            float4 aa0 = *(const float4*)&As[k][ty * 8];
            float4 aa1 = *(const float4*)&As[k][ty * 8 + 4];
            float4 bb  = *(const float4*)&Bs[k][tx * 4];
            float av[8] = {aa0.x, aa0.y, aa0.z, aa0.w, aa1.x, aa1.y, aa1.z, aa1.w};
            float bv[4] = {bb.x, bb.y, bb.z, bb.w};
#pragma unroll
            for (int i = 0; i < 8; ++i)
#pragma unroll
                for (int j = 0; j < 4; ++j) acc[i][j] += av[i] * bv[j];
        }
        __syncthreads();
    }

    float4 bv4 = *(const float4*)&bias[col0 + tx * 4];
    float bvv[4] = {bv4.x, bv4.y, bv4.z, bv4.w};
#pragma unroll
    for (int i = 0; i < 8; ++i) {
        int m = row0 + ty * 8 + i;
        float4 o = make_float4(acc[i][0] + bvv[0], acc[i][1] + bvv[1],
                               acc[i][2] + bvv[2], acc[i][3] + bvv[3]);
        int c = col0 + tx * 4;
        if (qkv) {
            int b = m >> 10, n = m & 1023;
            int hh = c >> 6, d = c & 63;
            *(float4*)&O[(((size_t)(b * NHEADS + hh) * NTOK + n) * DHEAD + d)] = o;
        } else {
            *(float4*)&O[(size_t)m * 1024 + c] = o;
        }
    }
}

// ---------------------------------------------------------------------------
// Kernel 3: fused attention per (b, h, 16-row q-tile).
//   S = qk^T/8 + bias(read from attnO) -> softmax -> attnO (final attn output)
//   out tile = attn @ v  -> ao in [B,N,DMODEL] layout
// LDS: Ss 64KB + shA 16KB (k-stage, aliased later as reduce buffer) = 80KB.
// ---------------------------------------------------------------------------
__global__ __launch_bounds__(256, 2) void attn_kernel(
    const float* __restrict__ qg, const float* __restrict__ kg, const float* __restrict__ vg,
    float* __restrict__ attnO, float* __restrict__ ao)
{
    __shared__ float Ss[16 * 1024];
    __shared__ float shA[64 * 64];

    int tid = threadIdx.x;
    int qt = blockIdx.x, hh = blockIdx.y, b = blockIdx.z;
    int bh = b * NHEADS + hh;
    const float* qb = qg + ((size_t)bh * NTOK + qt * 16) * DHEAD;
    const float* kb = kg + (size_t)bh * NTOK * DHEAD;
    const float* vb = vg + (size_t)bh * NTOK * DHEAD;
    float* attnRow = attnO + ((size_t)bh * NTOK + qt * 16) * NTOK;

    int tx = tid & 15, ty = tid >> 4;

    // q row (row = ty) into registers; 16 lanes of same ty broadcast via cache
    float4 q4[16];
#pragma unroll
    for (int dc = 0; dc < 16; ++dc)
        q4[dc] = *(const float4*)&qb[ty * DHEAD + dc * 4];

    // ---- S phase: j-tiles of 64 ----
    for (int jt = 0; jt < 16; ++jt) {
        __syncthreads();
        // stage k tile [64][64], XOR-swizzled f4 slots: slot = c4 ^ ((row>>2)&15)
#pragma unroll
        for (int t = 0; t < 4; ++t) {
            int id  = tid + t * 256;
            int row = id >> 4;
            int c4  = id & 15;
            float4 kv = *(const float4*)&kb[(size_t)(jt * 64 + row) * DHEAD + c4 * 4];
            int sl = c4 ^ ((row >> 2) & 15);
            *(float4*)&shA[row * 64 + sl * 4] = kv;
        }
        __syncthreads();
        float acc0 = 0.f, acc1 = 0.f, acc2 = 0.f, acc3 = 0.f;
#pragma unroll
        for (int dc = 0; dc < 16; ++dc) {
            float4 qv = q4[dc];
            int sl = ((dc ^ tx) & 15) * 4;
            float4 k0 = *(const float4*)&shA[(tx * 4 + 0) * 64 + sl];
            float4 k1 = *(const float4*)&shA[(tx * 4 + 1) * 64 + sl];
            float4 k2 = *(const float4*)&shA[(tx * 4 + 2) * 64 + sl];
            float4 k3 = *(const float4*)&shA[(tx * 4 + 3) * 64 + sl];
            acc0 += qv.x * k0.x + qv.y * k0.y + qv.z * k0.z + qv.w * k0.w;
            acc1 += qv.x * k1.x + qv.y * k1.y + qv.z * k1.z + qv.w * k1.w;
            acc2 += qv.x * k2.x + qv.y * k2.y + qv.z * k2.z + qv.w * k2.w;
            acc3 += qv.x * k3.x + qv.y * k3.y + qv.z * k3.z + qv.w * k3.w;
        }
        int j0 = jt * 64 + tx * 4;
        float4 b4 = *(const float4*)&attnRow[(size_t)ty * NTOK + j0];
        float4 s4 = make_float4(acc0 * 0.125f + b4.x, acc1 * 0.125f + b4.y,
                                acc2 * 0.125f + b4.z, acc3 * 0.125f + b4.w);
        *(float4*)&Ss[ty * 1024 + j0] = s4;
    }
    __syncthreads();

    // ---- softmax: wave w owns rows 4w..4w+3 ----
    int w = tid >> 6, lane = tid & 63;
#pragma unroll
    for (int ri = 0; ri < 4; ++ri) {
        int r = w * 4 + ri;
        float e[16];
#pragma unroll
        for (int qd = 0; qd < 4; ++qd) {
            float4 v = *(const float4*)&Ss[r * 1024 + qd * 256 + lane * 4];
            e[qd * 4 + 0] = v.x; e[qd * 4 + 1] = v.y;
            e[qd * 4 + 2] = v.z; e[qd * 4 + 3] = v.w;
        }
        float m = -1e30f;
#pragma unroll
        for (int t = 0; t < 16; ++t) m = fmaxf(m, e[t]);
#pragma unroll
        for (int s = 1; s < 64; s <<= 1) m = fmaxf(m, __shfl_xor(m, s, 64));
        float sum = 0.f;
#pragma unroll
        for (int t = 0; t < 16; ++t) { e[t] = __expf(e[t] - m); sum += e[t]; }
#pragma unroll
        for (int s = 1; s < 64; s <<= 1) sum += __shfl_xor(sum, s, 64);
        float inv = 1.0f / sum;
#pragma unroll
        for (int qd = 0; qd < 4; ++qd) {
            float4 p = make_float4(e[qd * 4 + 0] * inv, e[qd * 4 + 1] * inv,
                                   e[qd * 4 + 2] * inv, e[qd * 4 + 3] * inv);
            *(float4*)&Ss[r * 1024 + qd * 256 + lane * 4] = p;
            *(float4*)&attnRow[(size_t)r * NTOK + qd * 256 + lane * 4] = p;
        }
    }
    __syncthreads();

    // ---- PV: wave w covers k-slice [w*256, w*256+256); lane=(tx2, ty2) ----
    int tx2 = lane & 15, ty2 = lane >> 4;
    float acc[16][4];
#pragma unroll
    for (int r = 0; r < 16; ++r) {
        acc[r][0] = 0.f; acc[r][1] = 0.f; acc[r][2] = 0.f; acc[r][3] = 0.f;
    }
    int jbase = w * 256 + ty2 * 64;
    for (int jl = 0; jl < 64; jl += 4) {
        int j = jbase + jl;
        float4 v0 = *(const float4*)&vb[(size_t)(j + 0) * DHEAD + tx2 * 4];
        float4 v1 = *(const float4*)&vb[(size_t)(j + 1) * DHEAD + tx2 * 4];
        float4 v2 = *(const float4*)&vb[(size_t)(j + 2) * DHEAD + tx2 * 4];
        float4 v3 = *(const float4*)&vb[(size_t)(j + 3) * DHEAD + tx2 * 4];
#pragma unroll
        for (int r = 0; r < 16; ++r) {
            float4 s4 = *(const float4*)&Ss[r * 1024 + j];
            acc[r][0] += s4.x * v0.x + s4.y * v1.x + s4.z * v2.x + s4.w * v3.x;
            acc[r][1] += s4.x * v0.y + s4.y * v1.y + s4.z * v2.y + s4.w * v3.y;
            acc[r][2] += s4.x * v0.z + s4.y * v1.z + s4.z * v2.z + s4.w * v3.z;
            acc[r][3] += s4.x * v0.w + s4.y * v1.w + s4.z * v2.w + s4.w * v3.w;
        }
    }
    // reduce across ty2 (lanes 16, 32 apart) within wave
#pragma unroll
    for (int r = 0; r < 16; ++r)
#pragma unroll
        for (int c = 0; c < 4; ++c) {
            float v = acc[r][c];
            v += __shfl_xor(v, 16, 64);
            v += __shfl_xor(v, 32, 64);
            acc[r][c] = v;
        }
    // cross-wave partials in shA (k-stage buffer is dead now)
#pragma unroll
    for (int rr = 0; rr < 4; ++rr) {
        int r = ty2 * 4 + rr;
        *(float4*)&shA[(w * 16 + r) * 64 + tx2 * 4] =
            make_float4(acc[r][0], acc[r][1], acc[r][2], acc[r][3]);
    }
    __syncthreads();
    {
        int r = tid >> 4, c4 = tid & 15;
        float4 s = make_float4(0.f, 0.f, 0.f, 0.f);
#pragma unroll
        for (int ww = 0; ww < 4; ++ww) {
            float4 t = *(const float4*)&shA[(ww * 16 + r) * 64 + c4 * 4];
            s.x += t.x; s.y += t.y; s.z += t.z; s.w += t.w;
        }
        *(float4*)&ao[((size_t)(b * NTOK + qt * 16 + r)) * DMODEL + hh * DHEAD + c4 * 4] = s;
    }
}

// ---------------------------------------------------------------------------
extern "C" void kernel_launch(void* const* d_in, const int* in_sizes, int n_in,
                              void* d_out, int out_size, void* d_ws, size_t ws_size,
                              hipStream_t stream)
{
    const float* x   = (const float*)d_in[0];
    const float* xyz = (const float*)d_in[1];
    const float* Wq  = (const float*)d_in[2];
    const float* bq  = (const float*)d_in[3];
    const float* Wk  = (const float*)d_in[4];
    const float* bk  = (const float*)d_in[5];
    const float* Wv  = (const float*)d_in[6];
    const float* bv  = (const float*)d_in[7];
    const float* Wo  = (const float*)d_in[8];
    const float* bo  = (const float*)d_in[9];
    const float* W1  = (const float*)d_in[10];
    const float* b1  = (const float*)d_in[11];
    const float* W2  = (const float*)d_in[12];
    const float* b2  = (const float*)d_in[13];

    const size_t OUT_ELEMS = (size_t)2 * NTOK * DMODEL;     // 2,097,152
    float* out   = (float*)d_out;
    float* attnO = out + OUT_ELEMS;                          // [B,H,N,N]

    float* qw = (float*)d_ws;
    float* kw = qw + OUT_ELEMS;
    float* vw = kw + OUT_ELEMS;
    float* aw = vw + OUT_ELEMS;                              // attn@v in [B,N,D]

    // 1) bias MLP -> attn region of d_out
    bias_kernel<<<dim3(4, 1024, 2), 256, 0, stream>>>(xyz, W1, b1, W2, b2, attnO);
    // 2) q,k,v projections
    gemm_kernel<<<dim3(16, 16, 3), 256, 0, stream>>>(x, Wq, bq, Wk, bk, Wv, bv,
                                                     qw, kw, vw, 1);
    // 3) fused attention (writes attn output + PV result)
    attn_kernel<<<dim3(64, 16, 2), 256, 0, stream>>>(qw, kw, vw, attnO, aw);
    // 4) output projection
    gemm_kernel<<<dim3(16, 16, 1), 256, 0, stream>>>(aw, Wo, bo, Wo, bo, Wo, bo,
                                                     out, out, out, 0);
}

// Round 5
// 529.601 us; speedup vs baseline: 1.8854x; 1.8854x over previous
//
#include <hip/hip_runtime.h>
#include <hip/hip_bf16.h>
#include <math.h>

#define NTOK   1024
#define DMODEL 1024
#define NHEADS 16
#define DHEAD  64

typedef __attribute__((ext_vector_type(8))) short short8;
typedef __attribute__((ext_vector_type(4))) float floatx4;
#define MFMA(a,b,c) __builtin_amdgcn_mfma_f32_16x16x32_bf16(a,b,c,0,0,0)

// split f into bf16 hi + bf16 lo (hi = RNE(f), lo = RNE(f - hi)); hi+lo ~ 16-bit mantissa
__device__ __forceinline__ void bf16_split(float f, ushort& h, ushort& l) {
    unsigned u = __float_as_uint(f);
    unsigned hr = (u + 0x7FFFu + ((u >> 16) & 1u)) >> 16;
    h = (ushort)hr;
    float fh = __uint_as_float(hr << 16);
    float res = f - fh;
    unsigned u2 = __float_as_uint(res);
    l = (ushort)((u2 + 0x7FFFu + ((u2 >> 16) & 1u)) >> 16);
}

// ---------------------------------------------------------------------------
// Kernel 1: geometric bias MLP (unchanged, known-good).
// ---------------------------------------------------------------------------
__global__ __launch_bounds__(256) void bias_kernel(
    const float* __restrict__ xyz,
    const float* __restrict__ W1, const float* __restrict__ b1,
    const float* __restrict__ W2, const float* __restrict__ b2,
    float* __restrict__ attnO)
{
    __shared__ float wbuf[656];
    int tid = threadIdx.x;
    for (int i = tid; i < 656; i += 256) {
        float v;
        if (i < 96)       v = W1[i];
        else if (i < 128) v = b1[i - 96];
        else if (i < 640) v = W2[i - 128];
        else              v = b2[i - 640];
        wbuf[i] = v;
    }
    __syncthreads();
    const float* w1s = wbuf;
    const float* b1s = wbuf + 96;
    const float* w2s = wbuf + 128;
    const float* b2s = wbuf + 640;

    int j = blockIdx.x * 256 + tid;
    int i = blockIdx.y;
    int b = blockIdx.z;

    float xi0 = xyz[((size_t)b * NTOK + i) * 3 + 0];
    float xi1 = xyz[((size_t)b * NTOK + i) * 3 + 1];
    float xi2 = xyz[((size_t)b * NTOK + i) * 3 + 2];
    float d0 = xi0 - xyz[((size_t)b * NTOK + j) * 3 + 0];
    float d1 = xi1 - xyz[((size_t)b * NTOK + j) * 3 + 1];
    float d2 = xi2 - xyz[((size_t)b * NTOK + j) * 3 + 2];

    float h[32];
#pragma unroll
    for (int hh = 0; hh < 32; ++hh) {
        float v = b1s[hh] + d0 * w1s[hh] + d1 * w1s[32 + hh] + d2 * w1s[64 + hh];
        h[hh] = fmaxf(v, 0.f);
    }
    size_t base = (size_t)b * NHEADS * 1048576 + (size_t)i * 1024 + j;
#pragma unroll
    for (int hd = 0; hd < NHEADS; ++hd) {
        float acc = b2s[hd];
#pragma unroll
        for (int hh = 0; hh < 32; ++hh) acc += h[hh] * w2s[hh * 16 + hd];
        attnO[base + (size_t)hd * 1048576] = acc;
    }
}

// ---------------------------------------------------------------------------
// Kernel C1: x fp32 -> xh/xl bf16 (same [2048][1024] layout).
// ---------------------------------------------------------------------------
__global__ __launch_bounds__(256) void convx_kernel(
    const float* __restrict__ x, ushort* __restrict__ xh, ushort* __restrict__ xl)
{
    int id = blockIdx.x * 256 + threadIdx.x;      // 0..524287, 4 floats each
    float4 v = ((const float4*)x)[id];
    ushort h0,h1,h2,h3,l0,l1,l2,l3;
    bf16_split(v.x,h0,l0); bf16_split(v.y,h1,l1);
    bf16_split(v.z,h2,l2); bf16_split(v.w,h3,l3);
    ushort4 hv; hv.x=h0; hv.y=h1; hv.z=h2; hv.w=h3;
    ushort4 lv; lv.x=l0; lv.y=l1; lv.z=l2; lv.w=l3;
    ((ushort4*)xh)[id] = hv;
    ((ushort4*)xl)[id] = lv;
}

// ---------------------------------------------------------------------------
// Kernel C2: weight transpose+convert. z=0..2: Wq/Wk/Wv -> Wcat_t[3072][1024];
// z=3: Wo -> Wot[1024][1024]. Output layout: [n][k] bf16 hi/lo.
// ---------------------------------------------------------------------------
__global__ __launch_bounds__(256) void convw_kernel(
    const float* __restrict__ Wq, const float* __restrict__ Wk,
    const float* __restrict__ Wv, const float* __restrict__ Wo,
    ushort* __restrict__ Wcth, ushort* __restrict__ Wctl,
    ushort* __restrict__ Woth, ushort* __restrict__ Wotl)
{
    __shared__ float t[64][65];
    int z = blockIdx.z;
    const float* W = (z == 0) ? Wq : (z == 1) ? Wk : (z == 2) ? Wv : Wo;
    int n0 = blockIdx.x * 64, k0 = blockIdx.y * 64;
    int tid = threadIdx.x;
    int c4 = tid & 15, rr = tid >> 4;
#pragma unroll
    for (int t4 = 0; t4 < 4; ++t4) {
        int row = rr + t4 * 16;                  // k-local
        float4 v = *(const float4*)&W[(size_t)(k0 + row) * 1024 + n0 + c4 * 4];
        t[row][c4 * 4 + 0] = v.x; t[row][c4 * 4 + 1] = v.y;
        t[row][c4 * 4 + 2] = v.z; t[row][c4 * 4 + 3] = v.w;
    }
    __syncthreads();
    ushort* oh = (z < 3) ? Wcth : Woth;
    ushort* ol = (z < 3) ? Wctl : Wotl;
    int nbase = (z < 3) ? z * 1024 : 0;
#pragma unroll
    for (int t4 = 0; t4 < 4; ++t4) {
        int nl = rr + t4 * 16;                   // n-local
        int kk = c4 * 4;
        ushort4 hv, lv;
        ushort h, l;
        bf16_split(t[kk + 0][nl], h, l); hv.x = h; lv.x = l;
        bf16_split(t[kk + 1][nl], h, l); hv.y = h; lv.y = l;
        bf16_split(t[kk + 2][nl], h, l); hv.z = h; lv.z = l;
        bf16_split(t[kk + 3][nl], h, l); hv.w = h; lv.w = l;
        size_t o = (size_t)(nbase + n0 + nl) * 1024 + k0 + kk;
        *(ushort4*)&oh[o] = hv;
        *(ushort4*)&ol[o] = lv;
    }
}

// ---------------------------------------------------------------------------
// Kernel G: split-bf16 MFMA GEMM. C[M x N] = A[M x 1024] @ B^T (B stored [n][k]).
// Block 256 thr / 4 waves; tile 128(M) x 64(N); wave w: rows w*32..w*32+31.
// mode 0: out[row*1024+col] = acc + bo[col]   (out-proj)
// mode 1: QKV epilogue -> qh/ql, kh/kl (bf16 [bh][n][64]), vth/vtl ([bh][64][1024])
// ---------------------------------------------------------------------------
__global__ __launch_bounds__(256) void mm_kernel(
    const ushort* __restrict__ Ah, const ushort* __restrict__ Al,
    const ushort* __restrict__ Bh, const ushort* __restrict__ Bl,
    const float* __restrict__ bq, const float* __restrict__ bk,
    const float* __restrict__ bv,
    float* __restrict__ out,
    ushort* __restrict__ qh, ushort* __restrict__ ql,
    ushort* __restrict__ kh, ushort* __restrict__ kl,
    ushort* __restrict__ vth, ushort* __restrict__ vtl,
    int mode)
{
    int n0 = blockIdx.x * 64;
    int m0 = blockIdx.y * 128;
    int w = threadIdx.x >> 6, l = threadIdx.x & 63;
    int li = l & 15, lg = l >> 4;
    int mrow = m0 + w * 32;

    const ushort* a0h = Ah + (size_t)(mrow + li) * 1024;
    const ushort* a0l = Al + (size_t)(mrow + li) * 1024;
    const ushort* a1h = Ah + (size_t)(mrow + 16 + li) * 1024;
    const ushort* a1l = Al + (size_t)(mrow + 16 + li) * 1024;
    const ushort* b0h = Bh + (size_t)(n0 +  0 + li) * 1024;
    const ushort* b1h = Bh + (size_t)(n0 + 16 + li) * 1024;
    const ushort* b2h = Bh + (size_t)(n0 + 32 + li) * 1024;
    const ushort* b3h = Bh + (size_t)(n0 + 48 + li) * 1024;
    const ushort* b0l = Bl + (size_t)(n0 +  0 + li) * 1024;
    const ushort* b1l = Bl + (size_t)(n0 + 16 + li) * 1024;
    const ushort* b2l = Bl + (size_t)(n0 + 32 + li) * 1024;
    const ushort* b3l = Bl + (size_t)(n0 + 48 + li) * 1024;

    floatx4 acc[2][4];
#pragma unroll
    for (int i = 0; i < 2; ++i)
#pragma unroll
        for (int j = 0; j < 4; ++j) acc[i][j] = (floatx4){0.f, 0.f, 0.f, 0.f};

    for (int ks = 0; ks < 32; ++ks) {
        int ko = ks * 32 + lg * 8;
        short8 A0h = *(const short8*)(a0h + ko);
        short8 A0l = *(const short8*)(a0l + ko);
        short8 A1h = *(const short8*)(a1h + ko);
        short8 A1l = *(const short8*)(a1l + ko);
#pragma unroll
        for (int nf = 0; nf < 4; ++nf) {
            const ushort* bhp = (nf == 0) ? b0h : (nf == 1) ? b1h : (nf == 2) ? b2h : b3h;
            const ushort* blp = (nf == 0) ? b0l : (nf == 1) ? b1l : (nf == 2) ? b2l : b3l;
            short8 Bh8 = *(const short8*)(bhp + ko);
            short8 Bl8 = *(const short8*)(blp + ko);
            acc[0][nf] = MFMA(A0h, Bh8, acc[0][nf]);
            acc[0][nf] = MFMA(A0h, Bl8, acc[0][nf]);
            acc[0][nf] = MFMA(A0l, Bh8, acc[0][nf]);
            acc[1][nf] = MFMA(A1h, Bh8, acc[1][nf]);
            acc[1][nf] = MFMA(A1h, Bl8, acc[1][nf]);
            acc[1][nf] = MFMA(A1l, Bh8, acc[1][nf]);
        }
    }

    if (mode == 0) {
#pragma unroll
        for (int fm = 0; fm < 2; ++fm)
#pragma unroll
            for (int nf = 0; nf < 4; ++nf) {
                int col = n0 + nf * 16 + li;
                float bval = bq[col];
#pragma unroll
                for (int r = 0; r < 4; ++r) {
                    int row = mrow + fm * 16 + lg * 4 + r;
                    out[(size_t)row * 1024 + col] = acc[fm][nf][r] + bval;
                }
            }
    } else {
        int z = n0 >> 10;
        const float* bp = (z == 0) ? bq : (z == 1) ? bk : bv;
#pragma unroll
        for (int fm = 0; fm < 2; ++fm)
#pragma unroll
            for (int nf = 0; nf < 4; ++nf) {
                int col = n0 + nf * 16 + li;
                int nloc = col & 1023;
                int hd = nloc >> 6, d = nloc & 63;
                float bval = bp[nloc];
#pragma unroll
                for (int r = 0; r < 4; ++r) {
                    int row = mrow + fm * 16 + lg * 4 + r;
                    int b = row >> 10, nn = row & 1023;
                    int bh = b * NHEADS + hd;
                    float v = acc[fm][nf][r] + bval;
                    ushort h, lo; bf16_split(v, h, lo);
                    if (z == 0) {
                        size_t o = ((size_t)bh * NTOK + nn) * DHEAD + d;
                        qh[o] = h; ql[o] = lo;
                    } else if (z == 1) {
                        size_t o = ((size_t)bh * NTOK + nn) * DHEAD + d;
                        kh[o] = h; kl[o] = lo;
                    } else {
                        size_t o = ((size_t)bh * DHEAD + d) * NTOK + nn;
                        vth[o] = h; vtl[o] = lo;
                    }
                }
            }
    }
}

// ---------------------------------------------------------------------------
// Kernel AT: scores + softmax. Block = (qt 16 rows, h, b); 4 waves; wave w owns
// keys [w*256, w*256+256). S = (q.k^T)/8 + bias (read in-place from attnO),
// softmax over full row, write P fp32 back to attnO.
// ---------------------------------------------------------------------------
__global__ __launch_bounds__(256) void score_kernel(
    const ushort* __restrict__ qh, const ushort* __restrict__ ql,
    const ushort* __restrict__ kh, const ushort* __restrict__ kl,
    float* __restrict__ attnO)
{
    __shared__ float redM[4][16];
    __shared__ float redS[4][16];
    int qt = blockIdx.x, hd = blockIdx.y, b = blockIdx.z;
    int bh = b * NHEADS + hd;
    int w = threadIdx.x >> 6, l = threadIdx.x & 63;
    int li = l & 15, lg = l >> 4;

    size_t qoff = ((size_t)bh * NTOK + qt * 16 + li) * DHEAD + lg * 8;
    short8 q0h = *(const short8*)(qh + qoff);
    short8 q0l = *(const short8*)(ql + qoff);
    short8 q1h = *(const short8*)(qh + qoff + 32);
    short8 q1l = *(const short8*)(ql + qoff + 32);

    floatx4 acc[16];
#pragma unroll
    for (int jf = 0; jf < 16; ++jf) acc[jf] = (floatx4){0.f, 0.f, 0.f, 0.f};

    int jbase = w * 256;
#pragma unroll
    for (int jf = 0; jf < 16; ++jf) {
        size_t koff = ((size_t)bh * NTOK + jbase + jf * 16 + li) * DHEAD + lg * 8;
        short8 K0h = *(const short8*)(kh + koff);
        short8 K0l = *(const short8*)(kl + koff);
        short8 K1h = *(const short8*)(kh + koff + 32);
        short8 K1l = *(const short8*)(kl + koff + 32);
        acc[jf] = MFMA(q0h, K0h, acc[jf]);
        acc[jf] = MFMA(q0h, K0l, acc[jf]);
        acc[jf] = MFMA(q0l, K0h, acc[jf]);
        acc[jf] = MFMA(q1h, K1h, acc[jf]);
        acc[jf] = MFMA(q1h, K1l, acc[jf]);
        acc[jf] = MFMA(q1l, K1h, acc[jf]);
    }

    float* prow = attnO + ((size_t)bh * NTOK + qt * 16) * NTOK;

    float mloc[4] = {-1e30f, -1e30f, -1e30f, -1e30f};
#pragma unroll
    for (int jf = 0; jf < 16; ++jf)
#pragma unroll
        for (int r = 0; r < 4; ++r) {
            float s = acc[jf][r] * 0.125f
                    + prow[(size_t)(lg * 4 + r) * NTOK + jbase + jf * 16 + li];
            acc[jf][r] = s;
            mloc[r] = fmaxf(mloc[r], s);
        }
#pragma unroll
    for (int r = 0; r < 4; ++r) {
        float m = mloc[r];
        m = fmaxf(m, __shfl_xor(m, 1, 64));
        m = fmaxf(m, __shfl_xor(m, 2, 64));
        m = fmaxf(m, __shfl_xor(m, 4, 64));
        m = fmaxf(m, __shfl_xor(m, 8, 64));
        mloc[r] = m;
    }
    if (li == 0) {
#pragma unroll
        for (int r = 0; r < 4; ++r) redM[w][lg * 4 + r] = mloc[r];
    }
    __syncthreads();
    float M[4];
#pragma unroll
    for (int r = 0; r < 4; ++r) {
        int row = lg * 4 + r;
        M[r] = fmaxf(fmaxf(redM[0][row], redM[1][row]),
                     fmaxf(redM[2][row], redM[3][row]));
    }
    float sloc[4] = {0.f, 0.f, 0.f, 0.f};
#pragma unroll
    for (int jf = 0; jf < 16; ++jf)
#pragma unroll
        for (int r = 0; r < 4; ++r) {
            float e = __expf(acc[jf][r] - M[r]);
            acc[jf][r] = e;
            sloc[r] += e;
        }
#pragma unroll
    for (int r = 0; r < 4; ++r) {
        float s = sloc[r];
        s += __shfl_xor(s, 1, 64);
        s += __shfl_xor(s, 2, 64);
        s += __shfl_xor(s, 4, 64);
        s += __shfl_xor(s, 8, 64);
        sloc[r] = s;
    }
    if (li == 0) {
#pragma unroll
        for (int r = 0; r < 4; ++r) redS[w][lg * 4 + r] = sloc[r];
    }
    __syncthreads();
    float inv[4];
#pragma unroll
    for (int r = 0; r < 4; ++r) {
        int row = lg * 4 + r;
        inv[r] = 1.0f / (redS[0][row] + redS[1][row] + redS[2][row] + redS[3][row]);
    }
#pragma unroll
    for (int jf = 0; jf < 16; ++jf)
#pragma unroll
        for (int r = 0; r < 4; ++r)
            prow[(size_t)(lg * 4 + r) * NTOK + jbase + jf * 16 + li] = acc[jf][r] * inv[r];
}

// ---------------------------------------------------------------------------
// Kernel PV: out_head = P @ V per (bh, 128-row tile). A = P fp32 (from attnO,
// split to bf16 hi/lo in-register), B = vt hi/lo [bh][64][1024].
// Writes aw bf16 hi/lo in [row 2048][1024] layout for the out-proj GEMM.
// ---------------------------------------------------------------------------
__global__ __launch_bounds__(256) void pv_kernel(
    const float* __restrict__ attnP,
    const ushort* __restrict__ vth, const ushort* __restrict__ vtl,
    ushort* __restrict__ awh, ushort* __restrict__ awl)
{
    int mt = blockIdx.x;          // 0..7
    int bh = blockIdx.y;          // 0..31
    int b = bh >> 4, hd = bh & 15;
    int w = threadIdx.x >> 6, l = threadIdx.x & 63;
    int li = l & 15, lg = l >> 4;
    int mrow = mt * 128 + w * 32;

    const float* P0 = attnP + ((size_t)bh * NTOK + mrow + li) * NTOK;
    const float* P1 = attnP + ((size_t)bh * NTOK + mrow + 16 + li) * NTOK;
    const ushort* v0h = vth + ((size_t)bh * DHEAD +  0 + li) * NTOK;
    const ushort* v1h = vth + ((size_t)bh * DHEAD + 16 + li) * NTOK;
    const ushort* v2h = vth + ((size_t)bh * DHEAD + 32 + li) * NTOK;
    const ushort* v3h = vth + ((size_t)bh * DHEAD + 48 + li) * NTOK;
    const ushort* v0l = vtl + ((size_t)bh * DHEAD +  0 + li) * NTOK;
    const ushort* v1l = vtl + ((size_t)bh * DHEAD + 16 + li) * NTOK;
    const ushort* v2l = vtl + ((size_t)bh * DHEAD + 32 + li) * NTOK;
    const ushort* v3l = vtl + ((size_t)bh * DHEAD + 48 + li) * NTOK;

    floatx4 acc[2][4];
#pragma unroll
    for (int i = 0; i < 2; ++i)
#pragma unroll
        for (int j = 0; j < 4; ++j) acc[i][j] = (floatx4){0.f, 0.f, 0.f, 0.f};

    for (int ks = 0; ks < 32; ++ks) {
        int ko = ks * 32 + lg * 8;
        float pa[8], pb[8];
        {
            float4 t0 = *(const float4*)(P0 + ko);
            float4 t1 = *(const float4*)(P0 + ko + 4);
            pa[0]=t0.x; pa[1]=t0.y; pa[2]=t0.z; pa[3]=t0.w;
            pa[4]=t1.x; pa[5]=t1.y; pa[6]=t1.z; pa[7]=t1.w;
            float4 t2 = *(const float4*)(P1 + ko);
            float4 t3 = *(const float4*)(P1 + ko + 4);
            pb[0]=t2.x; pb[1]=t2.y; pb[2]=t2.z; pb[3]=t2.w;
            pb[4]=t3.x; pb[5]=t3.y; pb[6]=t3.z; pb[7]=t3.w;
        }
        short8 A0h, A0l, A1h, A1l;
#pragma unroll
        for (int e = 0; e < 8; ++e) {
            ushort h, lo;
            bf16_split(pa[e], h, lo); A0h[e] = (short)h; A0l[e] = (short)lo;
            bf16_split(pb[e], h, lo); A1h[e] = (short)h; A1l[e] = (short)lo;
        }
#pragma unroll
        for (int nf = 0; nf < 4; ++nf) {
            const ushort* vhp = (nf == 0) ? v0h : (nf == 1) ? v1h : (nf == 2) ? v2h : v3h;
            const ushort* vlp = (nf == 0) ? v0l : (nf == 1) ? v1l : (nf == 2) ? v2l : v3l;
            short8 Bh8 = *(const short8*)(vhp + ko);
            short8 Bl8 = *(const short8*)(vlp + ko);
            acc[0][nf] = MFMA(A0h, Bh8, acc[0][nf]);
            acc[0][nf] = MFMA(A0h, Bl8, acc[0][nf]);
            acc[0][nf] = MFMA(A0l, Bh8, acc[0][nf]);
            acc[1][nf] = MFMA(A1h, Bh8, acc[1][nf]);
            acc[1][nf] = MFMA(A1h, Bl8, acc[1][nf]);
            acc[1][nf] = MFMA(A1l, Bh8, acc[1][nf]);
        }
    }
#pragma unroll
    for (int fm = 0; fm < 2; ++fm)
#pragma unroll
        for (int nf = 0; nf < 4; ++nf)
#pragma unroll
            for (int r = 0; r < 4; ++r) {
                int token = mrow + fm * 16 + lg * 4 + r;   // within b-plane
                int d = nf * 16 + li;
                float v = acc[fm][nf][r];
                ushort h, lo; bf16_split(v, h, lo);
                size_t o = ((size_t)(b * NTOK + token)) * DMODEL + hd * DHEAD + d;
                awh[o] = h; awl[o] = lo;
            }
}

// ---------------------------------------------------------------------------
extern "C" void kernel_launch(void* const* d_in, const int* in_sizes, int n_in,
                              void* d_out, int out_size, void* d_ws, size_t ws_size,
                              hipStream_t stream)
{
    const float* x   = (const float*)d_in[0];
    const float* xyz = (const float*)d_in[1];
    const float* Wq  = (const float*)d_in[2];
    const float* bq  = (const float*)d_in[3];
    const float* Wk  = (const float*)d_in[4];
    const float* bk  = (const float*)d_in[5];
    const float* Wv  = (const float*)d_in[6];
    const float* bv  = (const float*)d_in[7];
    const float* Wo  = (const float*)d_in[8];
    const float* bo  = (const float*)d_in[9];
    const float* W1  = (const float*)d_in[10];
    const float* b1  = (const float*)d_in[11];
    const float* W2  = (const float*)d_in[12];
    const float* b2  = (const float*)d_in[13];

    const size_t OUT_ELEMS = (size_t)2 * NTOK * DMODEL;     // 2,097,152
    float* out   = (float*)d_out;
    float* attnO = out + OUT_ELEMS;                          // [B,H,N,N]

    // workspace layout (bytes)
    char* ws = (char*)d_ws;
    ushort* Wcth = (ushort*)(ws);                            //  6 MB [3072][1024]
    ushort* Wctl = (ushort*)(ws + 6291456);                  //  6 MB
    ushort* Woth = (ushort*)(ws + 12582912);                 //  2 MB [1024][1024]
    ushort* Wotl = (ushort*)(ws + 14680064);                 //  2 MB
    ushort* qh   = (ushort*)(ws + 16777216);                 //  4 MB [bh][n][64]
    ushort* ql   = (ushort*)(ws + 20971520);
    ushort* kh   = (ushort*)(ws + 25165824);
    ushort* kl   = (ushort*)(ws + 29360128);
    ushort* vth  = (ushort*)(ws + 33554432);                 //  4 MB [bh][64][n]
    ushort* vtl  = (ushort*)(ws + 37748736);
    ushort* xh   = (ushort*)(ws + 41943040);                 //  4 MB [2048][1024]
    ushort* xl   = (ushort*)(ws + 46137344);                 //  ends at 48 MB
    // aw aliases the x buffers (x is dead after the QKV GEMM)
    ushort* awh  = xh;
    ushort* awl  = xl;

    // 1) bias MLP -> attn region of d_out
    bias_kernel<<<dim3(4, 1024, 2), 256, 0, stream>>>(xyz, W1, b1, W2, b2, attnO);
    // 2) input conversions
    convx_kernel<<<dim3(2048), 256, 0, stream>>>(x, xh, xl);
    convw_kernel<<<dim3(16, 16, 4), 256, 0, stream>>>(Wq, Wk, Wv, Wo,
                                                      Wcth, Wctl, Woth, Wotl);
    // 3) fused QKV projection (M=2048, N=3072)
    mm_kernel<<<dim3(48, 16), 256, 0, stream>>>(xh, xl, Wcth, Wctl,
                                                bq, bk, bv, nullptr,
                                                qh, ql, kh, kl, vth, vtl, 1);
    // 4) scores + softmax -> attnO (final attn output)
    score_kernel<<<dim3(64, NHEADS, 2), 256, 0, stream>>>(qh, ql, kh, kl, attnO);
    // 5) P @ V -> aw (bf16 hi/lo)
    pv_kernel<<<dim3(8, 32), 256, 0, stream>>>(attnO, vth, vtl, awh, awl);
    // 6) output projection (M=2048, N=1024)
    mm_kernel<<<dim3(16, 16), 256, 0, stream>>>(awh, awl, Woth, Wotl,
                                                bo, bo, bo, out,
                                                nullptr, nullptr, nullptr, nullptr,
                                                nullptr, nullptr, 0);
}

// Round 7
// 427.781 us; speedup vs baseline: 2.3342x; 1.2380x over previous
//
#include <hip/hip_runtime.h>
#include <hip/hip_bf16.h>
#include <math.h>

#define NTOK   1024
#define DMODEL 1024
#define NHEADS 16
#define DHEAD  64

typedef __attribute__((ext_vector_type(8))) short short8;
typedef __attribute__((ext_vector_type(4))) float floatx4;
#define MFMA(a,b,c) __builtin_amdgcn_mfma_f32_16x16x32_bf16(a,b,c,0,0,0)

// split f into bf16 hi + bf16 lo (hi = RNE(f), lo = RNE(f - hi)); hi+lo ~ 16-bit mantissa
__device__ __forceinline__ void bf16_split(float f, ushort& h, ushort& l) {
    unsigned u = __float_as_uint(f);
    unsigned hr = (u + 0x7FFFu + ((u >> 16) & 1u)) >> 16;
    h = (ushort)hr;
    float fh = __uint_as_float(hr << 16);
    float res = f - fh;
    unsigned u2 = __float_as_uint(res);
    l = (ushort)((u2 + 0x7FFFu + ((u2 >> 16) & 1u)) >> 16);
}

// LDS chunk swizzle (16B chunks within a 128B row): 2-way-free banks
__device__ __forceinline__ int swzK(int r) { return (r & 7) ^ ((r >> 3) & 7); }

// ---------------------------------------------------------------------------
// Kernel 1: geometric bias MLP (unchanged, known-good).
// ---------------------------------------------------------------------------
__global__ __launch_bounds__(256) void bias_kernel(
    const float* __restrict__ xyz,
    const float* __restrict__ W1, const float* __restrict__ b1,
    const float* __restrict__ W2, const float* __restrict__ b2,
    float* __restrict__ attnO)
{
    __shared__ float wbuf[656];
    int tid = threadIdx.x;
    for (int i = tid; i < 656; i += 256) {
        float v;
        if (i < 96)       v = W1[i];
        else if (i < 128) v = b1[i - 96];
        else if (i < 640) v = W2[i - 128];
        else              v = b2[i - 640];
        wbuf[i] = v;
    }
    __syncthreads();
    const float* w1s = wbuf;
    const float* b1s = wbuf + 96;
    const float* w2s = wbuf + 128;
    const float* b2s = wbuf + 640;

    int j = blockIdx.x * 256 + tid;
    int i = blockIdx.y;
    int b = blockIdx.z;

    float xi0 = xyz[((size_t)b * NTOK + i) * 3 + 0];
    float xi1 = xyz[((size_t)b * NTOK + i) * 3 + 1];
    float xi2 = xyz[((size_t)b * NTOK + i) * 3 + 2];
    float d0 = xi0 - xyz[((size_t)b * NTOK + j) * 3 + 0];
    float d1 = xi1 - xyz[((size_t)b * NTOK + j) * 3 + 1];
    float d2 = xi2 - xyz[((size_t)b * NTOK + j) * 3 + 2];

    float h[32];
#pragma unroll
    for (int hh = 0; hh < 32; ++hh) {
        float v = b1s[hh] + d0 * w1s[hh] + d1 * w1s[32 + hh] + d2 * w1s[64 + hh];
        h[hh] = fmaxf(v, 0.f);
    }
    size_t base = (size_t)b * NHEADS * 1048576 + (size_t)i * 1024 + j;
#pragma unroll
    for (int hd = 0; hd < NHEADS; ++hd) {
        float acc = b2s[hd];
#pragma unroll
        for (int hh = 0; hh < 32; ++hh) acc += h[hh] * w2s[hh * 16 + hd];
        attnO[base + (size_t)hd * 1048576] = acc;
    }
}

// ---------------------------------------------------------------------------
// Kernel C1: x fp32 -> xh/xl bf16 (same [2048][1024] layout).
// ---------------------------------------------------------------------------
__global__ __launch_bounds__(256) void convx_kernel(
    const float* __restrict__ x, ushort* __restrict__ xh, ushort* __restrict__ xl)
{
    int id = blockIdx.x * 256 + threadIdx.x;      // 0..524287, 4 floats each
    float4 v = ((const float4*)x)[id];
    ushort h0,h1,h2,h3,l0,l1,l2,l3;
    bf16_split(v.x,h0,l0); bf16_split(v.y,h1,l1);
    bf16_split(v.z,h2,l2); bf16_split(v.w,h3,l3);
    ushort4 hv; hv.x=h0; hv.y=h1; hv.z=h2; hv.w=h3;
    ushort4 lv; lv.x=l0; lv.y=l1; lv.z=l2; lv.w=l3;
    ((ushort4*)xh)[id] = hv;
    ((ushort4*)xl)[id] = lv;
}

// ---------------------------------------------------------------------------
// Kernel C2: weight transpose+convert. z=0..2: Wq/Wk/Wv -> Wcat_t[3072][1024];
// z=3: Wo -> Wot[1024][1024]. Output layout: [n][k] bf16 hi/lo.
// ---------------------------------------------------------------------------
__global__ __launch_bounds__(256) void convw_kernel(
    const float* __restrict__ Wq, const float* __restrict__ Wk,
    const float* __restrict__ Wv, const float* __restrict__ Wo,
    ushort* __restrict__ Wcth, ushort* __restrict__ Wctl,
    ushort* __restrict__ Woth, ushort* __restrict__ Wotl)
{
    __shared__ float t[64][65];
    int z = blockIdx.z;
    const float* W = (z == 0) ? Wq : (z == 1) ? Wk : (z == 2) ? Wv : Wo;
    int n0 = blockIdx.x * 64, k0 = blockIdx.y * 64;
    int tid = threadIdx.x;
    int c4 = tid & 15, rr = tid >> 4;
#pragma unroll
    for (int t4 = 0; t4 < 4; ++t4) {
        int row = rr + t4 * 16;                  // k-local
        float4 v = *(const float4*)&W[(size_t)(k0 + row) * 1024 + n0 + c4 * 4];
        t[row][c4 * 4 + 0] = v.x; t[row][c4 * 4 + 1] = v.y;
        t[row][c4 * 4 + 2] = v.z; t[row][c4 * 4 + 3] = v.w;
    }
    __syncthreads();
    ushort* oh = (z < 3) ? Wcth : Woth;
    ushort* ol = (z < 3) ? Wctl : Wotl;
    int nbase = (z < 3) ? z * 1024 : 0;
#pragma unroll
    for (int t4 = 0; t4 < 4; ++t4) {
        int nl = rr + t4 * 16;                   // n-local
        int kk = c4 * 4;
        ushort4 hv, lv;
        ushort h, l;
        bf16_split(t[kk + 0][nl], h, l); hv.x = h; lv.x = l;
        bf16_split(t[kk + 1][nl], h, l); hv.y = h; lv.y = l;
        bf16_split(t[kk + 2][nl], h, l); hv.z = h; lv.z = l;
        bf16_split(t[kk + 3][nl], h, l); hv.w = h; lv.w = l;
        size_t o = (size_t)(nbase + n0 + nl) * 1024 + k0 + kk;
        *(ushort4*)&oh[o] = hv;
        *(ushort4*)&ol[o] = lv;
    }
}

// ---------------------------------------------------------------------------
// Kernel G: split-bf16 MFMA GEMM, LDS-staged via global_load_lds.
// C[M x N] = A[M x 1024] @ B^T (B stored [n][k] bf16 hi/lo).
// Tile 64(M) x 64(N), BK=64, 256 thr / 4 waves; wave (wm,wn) owns a 32x32
// quadrant (2x2 16x16 frags). LDS 32 KB: 4 comps (Ah,Al,Bh,Bl) x [64][64]
// ushort, 128B rows, chunk-swizzled: LDS[r][16B-chunk c] holds global chunk
// c ^ swzK(r)  (inverse-swizzled source, linear global_load_lds dest,
// swizzled ds_read -- same XOR both sides). 2-way banks = free.
// mode 0: out[row*1024+col] = acc + bo[col]   (out-proj)
// mode 1: QKV epilogue -> qh/ql, kh/kl (bf16 [bh][n][64]), vth/vtl ([bh][64][1024])
// ---------------------------------------------------------------------------
__global__ __launch_bounds__(256) void mm_kernel(
    const ushort* __restrict__ Ah, const ushort* __restrict__ Al,
    const ushort* __restrict__ Bh, const ushort* __restrict__ Bl,
    const float* __restrict__ bq, const float* __restrict__ bk,
    const float* __restrict__ bv,
    float* __restrict__ out,
    ushort* __restrict__ qh, ushort* __restrict__ ql,
    ushort* __restrict__ kh, ushort* __restrict__ kl,
    ushort* __restrict__ vth, ushort* __restrict__ vtl,
    int mode)
{
    __shared__ ushort lds[4][64][64];            // 32 KB

    int n0 = blockIdx.x * 64;
    int m0 = blockIdx.y * 64;
    int w = threadIdx.x >> 6, l = threadIdx.x & 63;
    int li = l & 15, lg = l >> 4;
    int wm = w >> 1, wn = w & 1;

    // wave w stages component w
    const ushort* gbase;
    if      (w == 0) gbase = Ah + (size_t)m0 * 1024;
    else if (w == 1) gbase = Al + (size_t)m0 * 1024;
    else if (w == 2) gbase = Bh + (size_t)n0 * 1024;
    else             gbase = Bl + (size_t)n0 * 1024;
    ushort* lbase = &lds[w][0][0];
    int srow = l >> 3;                           // 0..7 (row within 8-row chunk)
    int sc   = l & 7;                            // 16B chunk within 128B row

    floatx4 acc[2][2];
#pragma unroll
    for (int i = 0; i < 2; ++i)
#pragma unroll
        for (int j = 0; j < 2; ++j) acc[i][j] = (floatx4){0.f, 0.f, 0.f, 0.f};

    for (int ks = 0; ks < 16; ++ks) {
        int k0 = ks * 64;
        // ---- stage: 8 x global_load_lds (1 KB each = 8 rows of 128B) ----
#pragma unroll
        for (int t = 0; t < 8; ++t) {
            int rl = t * 8 + srow;
            int cs = sc ^ swzK(rl);
            const ushort* g = gbase + (size_t)rl * 1024 + k0 + cs * 8;
            __builtin_amdgcn_global_load_lds(
                (const __attribute__((address_space(1))) unsigned int*)g,
                (__attribute__((address_space(3))) unsigned int*)(lbase + t * 512),
                16, 0, 0);
        }
        __syncthreads();
        // ---- compute: 2 k-substeps of 32, 24 MFMA total ----
#pragma unroll
        for (int kk = 0; kk < 2; ++kk) {
            short8 a[2][2], b2[2][2];
#pragma unroll
            for (int f = 0; f < 2; ++f) {
                int ra = wm * 32 + f * 16 + li;
                int ca = ((kk * 4 + lg) ^ swzK(ra)) * 8;
                a[f][0] = *(const short8*)&lds[0][ra][ca];
                a[f][1] = *(const short8*)&lds[1][ra][ca];
                int rb = wn * 32 + f * 16 + li;
                int cb = ((kk * 4 + lg) ^ swzK(rb)) * 8;
                b2[f][0] = *(const short8*)&lds[2][rb][cb];
                b2[f][1] = *(const short8*)&lds[3][rb][cb];
            }
#pragma unroll
            for (int fm = 0; fm < 2; ++fm)
#pragma unroll
                for (int fn = 0; fn < 2; ++fn) {
                    acc[fm][fn] = MFMA(a[fm][0], b2[fn][0], acc[fm][fn]);
                    acc[fm][fn] = MFMA(a[fm][0], b2[fn][1], acc[fm][fn]);
                    acc[fm][fn] = MFMA(a[fm][1], b2[fn][0], acc[fm][fn]);
                }
        }
        __syncthreads();
    }

    if (mode == 0) {
#pragma unroll
        for (int fm = 0; fm < 2; ++fm)
#pragma unroll
            for (int fn = 0; fn < 2; ++fn) {
                int col = n0 + wn * 32 + fn * 16 + li;
                float bval = bq[col];
#pragma unroll
                for (int r = 0; r < 4; ++r) {
                    int row = m0 + wm * 32 + fm * 16 + lg * 4 + r;
                    out[(size_t)row * 1024 + col] = acc[fm][fn][r] + bval;
                }
            }
    } else {
        int z = n0 >> 10;
        const float* bp = (z == 0) ? bq : (z == 1) ? bk : bv;
#pragma unroll
        for (int fm = 0; fm < 2; ++fm)
#pragma unroll
            for (int fn = 0; fn < 2; ++fn) {
                int col = n0 + wn * 32 + fn * 16 + li;
                int nloc = col & 1023;
                int hd = nloc >> 6, d = nloc & 63;
                float bval = bp[nloc];
#pragma unroll
                for (int r = 0; r < 4; ++r) {
                    int row = m0 + wm * 32 + fm * 16 + lg * 4 + r;
                    int b = row >> 10, nn = row & 1023;
                    int bh = b * NHEADS + hd;
                    float v = acc[fm][fn][r] + bval;
                    ushort h, lo; bf16_split(v, h, lo);
                    if (z == 0) {
                        size_t o = ((size_t)bh * NTOK + nn) * DHEAD + d;
                        qh[o] = h; ql[o] = lo;
                    } else if (z == 1) {
                        size_t o = ((size_t)bh * NTOK + nn) * DHEAD + d;
                        kh[o] = h; kl[o] = lo;
                    } else {
                        size_t o = ((size_t)bh * DHEAD + d) * NTOK + nn;
                        vth[o] = h; vtl[o] = lo;
                    }
                }
            }
    }
}

// ---------------------------------------------------------------------------
// Kernel AT: scores + softmax. Block = (qt 16 rows, h, b); 4 waves; wave w owns
// keys [w*256, w*256+256). S = (q.k^T)/8 + bias (read in-place from attnO),
// softmax over full row, write P fp32 back to attnO.
// ---------------------------------------------------------------------------
__global__ __launch_bounds__(256) void score_kernel(
    const ushort* __restrict__ qh, const ushort* __restrict__ ql,
    const ushort* __restrict__ kh, const ushort* __restrict__ kl,
    float* __restrict__ attnO)
{
    __shared__ float redM[4][16];
    __shared__ float redS[4][16];
    int qt = blockIdx.x, hd = blockIdx.y, b = blockIdx.z;
    int bh = b * NHEADS + hd;
    int w = threadIdx.x >> 6, l = threadIdx.x & 63;
    int li = l & 15, lg = l >> 4;

    size_t qoff = ((size_t)bh * NTOK + qt * 16 + li) * DHEAD + lg * 8;
    short8 q0h = *(const short8*)(qh + qoff);
    short8 q0l = *(const short8*)(ql + qoff);
    short8 q1h = *(const short8*)(qh + qoff + 32);
    short8 q1l = *(const short8*)(ql + qoff + 32);

    floatx4 acc[16];
#pragma unroll
    for (int jf = 0; jf < 16; ++jf) acc[jf] = (floatx4){0.f, 0.f, 0.f, 0.f};

    int jbase = w * 256;
#pragma unroll
    for (int jf = 0; jf < 16; ++jf) {
        size_t koff = ((size_t)bh * NTOK + jbase + jf * 16 + li) * DHEAD + lg * 8;
        short8 K0h = *(const short8*)(kh + koff);
        short8 K0l = *(const short8*)(kl + koff);
        short8 K1h = *(const short8*)(kh + koff + 32);
        short8 K1l = *(const short8*)(kl + koff + 32);
        acc[jf] = MFMA(q0h, K0h, acc[jf]);
        acc[jf] = MFMA(q0h, K0l, acc[jf]);
        acc[jf] = MFMA(q0l, K0h, acc[jf]);
        acc[jf] = MFMA(q1h, K1h, acc[jf]);
        acc[jf] = MFMA(q1h, K1l, acc[jf]);
        acc[jf] = MFMA(q1l, K1h, acc[jf]);
    }

    float* prow = attnO + ((size_t)bh * NTOK + qt * 16) * NTOK;

    float mloc[4] = {-1e30f, -1e30f, -1e30f, -1e30f};
#pragma unroll
    for (int jf = 0; jf < 16; ++jf)
#pragma unroll
        for (int r = 0; r < 4; ++r) {
            float s = acc[jf][r] * 0.125f
                    + prow[(size_t)(lg * 4 + r) * NTOK + jbase + jf * 16 + li];
            acc[jf][r] = s;
            mloc[r] = fmaxf(mloc[r], s);
        }
#pragma unroll
    for (int r = 0; r < 4; ++r) {
        float m = mloc[r];
        m = fmaxf(m, __shfl_xor(m, 1, 64));
        m = fmaxf(m, __shfl_xor(m, 2, 64));
        m = fmaxf(m, __shfl_xor(m, 4, 64));
        m = fmaxf(m, __shfl_xor(m, 8, 64));
        mloc[r] = m;
    }
    if (li == 0) {
#pragma unroll
        for (int r = 0; r < 4; ++r) redM[w][lg * 4 + r] = mloc[r];
    }
    __syncthreads();
    float M[4];
#pragma unroll
    for (int r = 0; r < 4; ++r) {
        int row = lg * 4 + r;
        M[r] = fmaxf(fmaxf(redM[0][row], redM[1][row]),
                     fmaxf(redM[2][row], redM[3][row]));
    }
    float sloc[4] = {0.f, 0.f, 0.f, 0.f};
#pragma unroll
    for (int jf = 0; jf < 16; ++jf)
#pragma unroll
        for (int r = 0; r < 4; ++r) {
            float e = __expf(acc[jf][r] - M[r]);
            acc[jf][r] = e;
            sloc[r] += e;
        }
#pragma unroll
    for (int r = 0; r < 4; ++r) {
        float s = sloc[r];
        s += __shfl_xor(s, 1, 64);
        s += __shfl_xor(s, 2, 64);
        s += __shfl_xor(s, 4, 64);
        s += __shfl_xor(s, 8, 64);
        sloc[r] = s;
    }
    if (li == 0) {
#pragma unroll
        for (int r = 0; r < 4; ++r) redS[w][lg * 4 + r] = sloc[r];
    }
    __syncthreads();
    float inv[4];
#pragma unroll
    for (int r = 0; r < 4; ++r) {
        int row = lg * 4 + r;
        inv[r] = 1.0f / (redS[0][row] + redS[1][row] + redS[2][row] + redS[3][row]);
    }
#pragma unroll
    for (int jf = 0; jf < 16; ++jf)
#pragma unroll
        for (int r = 0; r < 4; ++r)
            prow[(size_t)(lg * 4 + r) * NTOK + jbase + jf * 16 + li] = acc[jf][r] * inv[r];
}

// ---------------------------------------------------------------------------
// Kernel PV: out_head = P @ V per (bh, 128-row tile). A = P fp32 (from attnO,
// split to bf16 hi/lo in-register), B = vt hi/lo [bh][64][1024].
// Writes aw bf16 hi/lo in [row 2048][1024] layout for the out-proj GEMM.
// ---------------------------------------------------------------------------
__global__ __launch_bounds__(256) void pv_kernel(
    const float* __restrict__ attnP,
    const ushort* __restrict__ vth, const ushort* __restrict__ vtl,
    ushort* __restrict__ awh, ushort* __restrict__ awl)
{
    int mt = blockIdx.x;          // 0..7
    int bh = blockIdx.y;          // 0..31
    int b = bh >> 4, hd = bh & 15;
    int w = threadIdx.x >> 6, l = threadIdx.x & 63;
    int li = l & 15, lg = l >> 4;
    int mrow = mt * 128 + w * 32;

    const float* P0 = attnP + ((size_t)bh * NTOK + mrow + li) * NTOK;
    const float* P1 = attnP + ((size_t)bh * NTOK + mrow + 16 + li) * NTOK;
    const ushort* v0h = vth + ((size_t)bh * DHEAD +  0 + li) * NTOK;
    const ushort* v1h = vth + ((size_t)bh * DHEAD + 16 + li) * NTOK;
    const ushort* v2h = vth + ((size_t)bh * DHEAD + 32 + li) * NTOK;
    const ushort* v3h = vth + ((size_t)bh * DHEAD + 48 + li) * NTOK;
    const ushort* v0l = vtl + ((size_t)bh * DHEAD +  0 + li) * NTOK;
    const ushort* v1l = vtl + ((size_t)bh * DHEAD + 16 + li) * NTOK;
    const ushort* v2l = vtl + ((size_t)bh * DHEAD + 32 + li) * NTOK;
    const ushort* v3l = vtl + ((size_t)bh * DHEAD + 48 + li) * NTOK;

    floatx4 acc[2][4];
#pragma unroll
    for (int i = 0; i < 2; ++i)
#pragma unroll
        for (int j = 0; j < 4; ++j) acc[i][j] = (floatx4){0.f, 0.f, 0.f, 0.f};

    for (int ks = 0; ks < 32; ++ks) {
        int ko = ks * 32 + lg * 8;
        float pa[8], pb[8];
        {
            float4 t0 = *(const float4*)(P0 + ko);
            float4 t1 = *(const float4*)(P0 + ko + 4);
            pa[0]=t0.x; pa[1]=t0.y; pa[2]=t0.z; pa[3]=t0.w;
            pa[4]=t1.x; pa[5]=t1.y; pa[6]=t1.z; pa[7]=t1.w;
            float4 t2 = *(const float4*)(P1 + ko);
            float4 t3 = *(const float4*)(P1 + ko + 4);
            pb[0]=t2.x; pb[1]=t2.y; pb[2]=t2.z; pb[3]=t2.w;
            pb[4]=t3.x; pb[5]=t3.y; pb[6]=t3.z; pb[7]=t3.w;
        }
        short8 A0h, A0l, A1h, A1l;
#pragma unroll
        for (int e = 0; e < 8; ++e) {
            ushort h, lo;
            bf16_split(pa[e], h, lo); A0h[e] = (short)h; A0l[e] = (short)lo;
            bf16_split(pb[e], h, lo); A1h[e] = (short)h; A1l[e] = (short)lo;
        }
#pragma unroll
        for (int nf = 0; nf < 4; ++nf) {
            const ushort* vhp = (nf == 0) ? v0h : (nf == 1) ? v1h : (nf == 2) ? v2h : v3h;
            const ushort* vlp = (nf == 0) ? v0l : (nf == 1) ? v1l : (nf == 2) ? v2l : v3l;
            short8 Bh8 = *(const short8*)(vhp + ko);
            short8 Bl8 = *(const short8*)(vlp + ko);
            acc[0][nf] = MFMA(A0h, Bh8, acc[0][nf]);
            acc[0][nf] = MFMA(A0h, Bl8, acc[0][nf]);
            acc[0][nf] = MFMA(A0l, Bh8, acc[0][nf]);
            acc[1][nf] = MFMA(A1h, Bh8, acc[1][nf]);
            acc[1][nf] = MFMA(A1h, Bl8, acc[1][nf]);
            acc[1][nf] = MFMA(A1l, Bh8, acc[1][nf]);
        }
    }
#pragma unroll
    for (int fm = 0; fm < 2; ++fm)
#pragma unroll
        for (int nf = 0; nf < 4; ++nf)
#pragma unroll
            for (int r = 0; r < 4; ++r) {
                int token = mrow + fm * 16 + lg * 4 + r;   // within b-plane
                int d = nf * 16 + li;
                float v = acc[fm][nf][r];
                ushort h, lo; bf16_split(v, h, lo);
                size_t o = ((size_t)(b * NTOK + token)) * DMODEL + hd * DHEAD + d;
                awh[o] = h; awl[o] = lo;
            }
}

// ---------------------------------------------------------------------------
extern "C" void kernel_launch(void* const* d_in, const int* in_sizes, int n_in,
                              void* d_out, int out_size, void* d_ws, size_t ws_size,
                              hipStream_t stream)
{
    const float* x   = (const float*)d_in[0];
    const float* xyz = (const float*)d_in[1];
    const float* Wq  = (const float*)d_in[2];
    const float* bq  = (const float*)d_in[3];
    const float* Wk  = (const float*)d_in[4];
    const float* bk  = (const float*)d_in[5];
    const float* Wv  = (const float*)d_in[6];
    const float* bv  = (const float*)d_in[7];
    const float* Wo  = (const float*)d_in[8];
    const float* bo  = (const float*)d_in[9];
    const float* W1  = (const float*)d_in[10];
    const float* b1  = (const float*)d_in[11];
    const float* W2  = (const float*)d_in[12];
    const float* b2  = (const float*)d_in[13];

    const size_t OUT_ELEMS = (size_t)2 * NTOK * DMODEL;     // 2,097,152
    float* out   = (float*)d_out;
    float* attnO = out + OUT_ELEMS;                          // [B,H,N,N]

    // workspace layout (bytes)
    char* ws = (char*)d_ws;
    ushort* Wcth = (ushort*)(ws);                            //  6 MB [3072][1024]
    ushort* Wctl = (ushort*)(ws + 6291456);                  //  6 MB
    ushort* Woth = (ushort*)(ws + 12582912);                 //  2 MB [1024][1024]
    ushort* Wotl = (ushort*)(ws + 14680064);                 //  2 MB
    ushort* qh   = (ushort*)(ws + 16777216);                 //  4 MB [bh][n][64]
    ushort* ql   = (ushort*)(ws + 20971520);
    ushort* kh   = (ushort*)(ws + 25165824);
    ushort* kl   = (ushort*)(ws + 29360128);
    ushort* vth  = (ushort*)(ws + 33554432);                 //  4 MB [bh][64][n]
    ushort* vtl  = (ushort*)(ws + 37748736);
    ushort* xh   = (ushort*)(ws + 41943040);                 //  4 MB [2048][1024]
    ushort* xl   = (ushort*)(ws + 46137344);                 //  ends at 48 MB
    // aw aliases the x buffers (x is dead after the QKV GEMM)
    ushort* awh  = xh;
    ushort* awl  = xl;

    // 1) bias MLP -> attn region of d_out
    bias_kernel<<<dim3(4, 1024, 2), 256, 0, stream>>>(xyz, W1, b1, W2, b2, attnO);
    // 2) input conversions
    convx_kernel<<<dim3(2048), 256, 0, stream>>>(x, xh, xl);
    convw_kernel<<<dim3(16, 16, 4), 256, 0, stream>>>(Wq, Wk, Wv, Wo,
                                                      Wcth, Wctl, Woth, Wotl);
    // 3) fused QKV projection (M=2048, N=3072), 64x64 tiles
    mm_kernel<<<dim3(48, 32), 256, 0, stream>>>(xh, xl, Wcth, Wctl,
                                                bq, bk, bv, nullptr,
                                                qh, ql, kh, kl, vth, vtl, 1);
    // 4) scores + softmax -> attnO (final attn output)
    score_kernel<<<dim3(64, NHEADS, 2), 256, 0, stream>>>(qh, ql, kh, kl, attnO);
    // 5) P @ V -> aw (bf16 hi/lo)
    pv_kernel<<<dim3(8, 32), 256, 0, stream>>>(attnO, vth, vtl, awh, awl);
    // 6) output projection (M=2048, N=1024), 64x64 tiles
    mm_kernel<<<dim3(16, 32), 256, 0, stream>>>(awh, awl, Woth, Wotl,
                                                bo, bo, bo, out,
                                                nullptr, nullptr, nullptr, nullptr,
                                                nullptr, nullptr, 0);
}